// Round 4
// baseline (160.404 us; speedup 1.0000x reference)
//
#include <hip/hip_runtime.h>
#include <math.h>

#define B_ 32
#define L_ 2048
#define D_ 1024
#define C_ 1024
#define WROWS 8            // rows per wave in fused kernel
#define BROWS 32           // rows per block (4 waves)
#define NCH (L_ / BROWS)   // 64 chunks per batch row

// ws float offsets:
//   v     : [B_, D_]          0
//   cb    : [B_]              32768
//   energ : [B_, L_]          32800
//   vpart : [16, B_, D_]      98336
//   pm    : [B_, NCH]         622624
//   ps    : [B_, NCH]         624672
//   pc    : [B_, NCH, D_]     626720
//   cnt   : ints at float-off 2723872  (cnt_dc[16], done[32])

// ---- K1: vpart tiles + last-block-per-dc reduction -> v, cb ----
__global__ __launch_bounds__(256) void k_prep(const float* __restrict__ q,
                                              const float* __restrict__ W,
                                              const float* __restrict__ bh,
                                              float* __restrict__ vpart,
                                              float* __restrict__ v,
                                              float* __restrict__ cb,
                                              int* __restrict__ cnt) {
    int cc = blockIdx.x, dc = blockIdx.y;
    int t  = threadIdx.x;
    __shared__ float qs[B_][65];                 // padded
    __shared__ int lastf;
    #pragma unroll
    for (int i = 0; i < 8; ++i) {
        int idx = t + i * 256;                   // 2048 = 32*64
        int b = idx >> 6, cl = idx & 63;
        qs[b][cl] = q[b * C_ + cc * 64 + cl];
    }
    __syncthreads();

    int dl4 = t & 15;
    int bg  = t >> 4;
    float4 a0 = {0,0,0,0}, a1 = {0,0,0,0};
    const float4* W4 = reinterpret_cast<const float4*>(W);
    for (int c = 0; c < 64; ++c) {
        float4 w = W4[(size_t)(cc * 64 + c) * (D_ / 4) + dc * 16 + dl4];
        float q0 = qs[bg * 2 + 0][c];
        float q1 = qs[bg * 2 + 1][c];
        a0.x = fmaf(q0, w.x, a0.x); a0.y = fmaf(q0, w.y, a0.y);
        a0.z = fmaf(q0, w.z, a0.z); a0.w = fmaf(q0, w.w, a0.w);
        a1.x = fmaf(q1, w.x, a1.x); a1.y = fmaf(q1, w.y, a1.y);
        a1.z = fmaf(q1, w.z, a1.z); a1.w = fmaf(q1, w.w, a1.w);
    }
    size_t base = ((size_t)cc * B_ + bg * 2) * D_ + dc * 64 + dl4 * 4;
    *reinterpret_cast<float4*>(vpart + base)      = a0;
    *reinterpret_cast<float4*>(vpart + base + D_) = a1;

    __syncthreads();
    if (t == 0) {
        __threadfence();                         // release vpart writes
        int old = atomicAdd(&cnt[dc], 1);
        lastf = (old == 15);
    }
    __syncthreads();
    if (!lastf) return;
    __threadfence();                             // acquire siblings' vpart

    #pragma unroll
    for (int i = 0; i < 8; ++i) {
        int idx = t + i * 256;                   // 2048 outputs (32b x 64d)
        int b = idx >> 6, dl = idx & 63;
        int d = dc * 64 + dl;
        float a = 0.f;
        #pragma unroll
        for (int c2 = 0; c2 < 16; ++c2)
            a += vpart[((size_t)c2 * B_ + b) * D_ + d];
        v[(size_t)b * D_ + d] = a;
    }
    if (dc == 0) {
        int b = t >> 3, l8 = t & 7;
        float s = 0.f;
        for (int c = l8; c < C_; c += 8) s += bh[c] * q[b * C_ + c];
        s += __shfl_xor(s, 4); s += __shfl_xor(s, 2); s += __shfl_xor(s, 1);
        if (l8 == 0) cb[b] = s;
    }
}

// ---- K2: fused energies + online-softmax partials; last block per b finalizes ----
__global__ __launch_bounds__(256) void k_mega(const float* __restrict__ seq,
                                              const float* __restrict__ v,
                                              const float* __restrict__ cb,
                                              const int* __restrict__ lenp,
                                              float* __restrict__ energ,
                                              float* __restrict__ pm,
                                              float* __restrict__ ps,
                                              float* __restrict__ pc,
                                              int* __restrict__ done,
                                              float* __restrict__ ctx,
                                              float* __restrict__ scores) {
    int b  = blockIdx.y;
    int ch = blockIdx.x;
    int len = lenp[b];
    int l0 = ch * BROWS;
    int t = threadIdx.x, wid = t >> 6, lane = t & 63;

    __shared__ float e_sm[BROWS];
    __shared__ float lm[4], ls[4];
    __shared__ float lc[4][D_];                  // 16 KB
    __shared__ float wgt[NCH];
    __shared__ float Msh, Ssh;
    __shared__ int lastf;

    if (l0 < len) {                              // block-uniform branch
        int lw0 = l0 + wid * WROWS;
        const float* vb = v + (size_t)b * D_;
        float4 v0 = *reinterpret_cast<const float4*>(vb +       lane * 4);
        float4 v1 = *reinterpret_cast<const float4*>(vb + 256 + lane * 4);
        float4 v2 = *reinterpret_cast<const float4*>(vb + 512 + lane * 4);
        float4 v3 = *reinterpret_cast<const float4*>(vb + 768 + lane * 4);
        float cbb = cb[b];

        float m = -INFINITY, s = 0.f;
        float c[16];
        #pragma unroll
        for (int i = 0; i < 16; ++i) c[i] = 0.f;

        if (lw0 < len) {
            #pragma unroll
            for (int r = 0; r < WROWS; ++r) {
                int l = lw0 + r;
                bool valid = l < len;
                const float* row = seq + ((size_t)b * L_ + l) * D_;
                float4 s0 = *reinterpret_cast<const float4*>(row +       lane * 4);
                float4 s1 = *reinterpret_cast<const float4*>(row + 256 + lane * 4);
                float4 s2 = *reinterpret_cast<const float4*>(row + 512 + lane * 4);
                float4 s3 = *reinterpret_cast<const float4*>(row + 768 + lane * 4);
                float acc = 0.f;
                acc = fmaf(s0.x, v0.x, acc); acc = fmaf(s0.y, v0.y, acc);
                acc = fmaf(s0.z, v0.z, acc); acc = fmaf(s0.w, v0.w, acc);
                acc = fmaf(s1.x, v1.x, acc); acc = fmaf(s1.y, v1.y, acc);
                acc = fmaf(s1.z, v1.z, acc); acc = fmaf(s1.w, v1.w, acc);
                acc = fmaf(s2.x, v2.x, acc); acc = fmaf(s2.y, v2.y, acc);
                acc = fmaf(s2.z, v2.z, acc); acc = fmaf(s2.w, v2.w, acc);
                acc = fmaf(s3.x, v3.x, acc); acc = fmaf(s3.y, v3.y, acc);
                acc = fmaf(s3.z, v3.z, acc); acc = fmaf(s3.w, v3.w, acc);
                #pragma unroll
                for (int off = 32; off; off >>= 1) acc += __shfl_xor(acc, off);
                float e = acc + cbb;
                if (lane == 0) e_sm[wid * WROWS + r] = e;
                float mnew  = valid ? fmaxf(m, e) : m;
                float scale = (m == mnew) ? 1.f : __expf(m - mnew);
                float p     = valid ? __expf(e - mnew) : 0.f;
                s = s * scale + p;
                c[ 0] = fmaf(p, s0.x, c[ 0] * scale); c[ 1] = fmaf(p, s0.y, c[ 1] * scale);
                c[ 2] = fmaf(p, s0.z, c[ 2] * scale); c[ 3] = fmaf(p, s0.w, c[ 3] * scale);
                c[ 4] = fmaf(p, s1.x, c[ 4] * scale); c[ 5] = fmaf(p, s1.y, c[ 5] * scale);
                c[ 6] = fmaf(p, s1.z, c[ 6] * scale); c[ 7] = fmaf(p, s1.w, c[ 7] * scale);
                c[ 8] = fmaf(p, s2.x, c[ 8] * scale); c[ 9] = fmaf(p, s2.y, c[ 9] * scale);
                c[10] = fmaf(p, s2.z, c[10] * scale); c[11] = fmaf(p, s2.w, c[11] * scale);
                c[12] = fmaf(p, s3.x, c[12] * scale); c[13] = fmaf(p, s3.y, c[13] * scale);
                c[14] = fmaf(p, s3.z, c[14] * scale); c[15] = fmaf(p, s3.w, c[15] * scale);
                m = mnew;
            }
        }

        {
            float4 w0 = {c[ 0], c[ 1], c[ 2], c[ 3]};
            float4 w1 = {c[ 4], c[ 5], c[ 6], c[ 7]};
            float4 w2 = {c[ 8], c[ 9], c[10], c[11]};
            float4 w3 = {c[12], c[13], c[14], c[15]};
            *reinterpret_cast<float4*>(&lc[wid][      lane * 4]) = w0;
            *reinterpret_cast<float4*>(&lc[wid][256 + lane * 4]) = w1;
            *reinterpret_cast<float4*>(&lc[wid][512 + lane * 4]) = w2;
            *reinterpret_cast<float4*>(&lc[wid][768 + lane * 4]) = w3;
            if (lane == 0) { lm[wid] = m; ls[wid] = s; }
        }
        __syncthreads();

        if (t < BROWS) energ[(size_t)b * L_ + l0 + t] = e_sm[t];

        float mb = fmaxf(fmaxf(lm[0], lm[1]), fmaxf(lm[2], lm[3]));
        float w0 = (lm[0] == mb) ? 1.f : __expf(lm[0] - mb);
        float w1 = (lm[1] == mb) ? 1.f : __expf(lm[1] - mb);
        float w2 = (lm[2] == mb) ? 1.f : __expf(lm[2] - mb);
        float w3 = (lm[3] == mb) ? 1.f : __expf(lm[3] - mb);
        float sb = w0 * ls[0] + w1 * ls[1] + w2 * ls[2] + w3 * ls[3];

        float4 a0 = *reinterpret_cast<const float4*>(&lc[0][t * 4]);
        float4 a1 = *reinterpret_cast<const float4*>(&lc[1][t * 4]);
        float4 a2 = *reinterpret_cast<const float4*>(&lc[2][t * 4]);
        float4 a3 = *reinterpret_cast<const float4*>(&lc[3][t * 4]);
        float4 o;
        o.x = w0 * a0.x + w1 * a1.x + w2 * a2.x + w3 * a3.x;
        o.y = w0 * a0.y + w1 * a1.y + w2 * a2.y + w3 * a3.y;
        o.z = w0 * a0.z + w1 * a1.z + w2 * a2.z + w3 * a3.z;
        o.w = w0 * a0.w + w1 * a1.w + w2 * a2.w + w3 * a3.w;

        size_t pidx = (size_t)b * NCH + ch;
        if (t == 0) { pm[pidx] = mb; ps[pidx] = sb; }
        *reinterpret_cast<float4*>(pc + pidx * D_ + t * 4) = o;
        __syncthreads();
    }

    // ---- last chunk block for this b finalizes it (deterministic result) ----
    if (t == 0) {
        __threadfence();                         // release pm/ps/pc/energ
        int old = atomicAdd(&done[b], 1);
        lastf = (old == NCH - 1);
    }
    __syncthreads();
    if (!lastf) return;
    __threadfence();                             // acquire siblings' writes

    int nch = (len + BROWS - 1) / BROWS;         // 1..64
    if (t < 64) {
        float mi = (t < nch) ? pm[(size_t)b * NCH + t] : -INFINITY;
        float si = (t < nch) ? ps[(size_t)b * NCH + t] : 0.f;
        float M = mi;
        #pragma unroll
        for (int off = 32; off; off >>= 1) M = fmaxf(M, __shfl_xor(M, off));
        float ew = (t < nch) ? __expf(mi - M) : 0.f;
        float S  = ew * si;
        #pragma unroll
        for (int off = 32; off; off >>= 1) S += __shfl_xor(S, off);
        if (t < nch) wgt[t] = ew / S;
        if (t == 0) { Msh = M; Ssh = S; }
    }
    __syncthreads();
    float M = Msh, invS = 1.f / Ssh;

    #pragma unroll
    for (int i = 0; i < 4; ++i) {
        int d = t + i * 256;
        float o = 0.f;
        for (int c2 = 0; c2 < nch; ++c2)
            o = fmaf(wgt[c2], pc[((size_t)b * NCH + c2) * D_ + d], o);
        ctx[(size_t)b * D_ + d] = o;
    }
    #pragma unroll
    for (int i = 0; i < 8; ++i) {
        int l = t + i * 256;
        float e = energ[(size_t)b * L_ + l];
        scores[(size_t)b * L_ + l] = (l < len) ? __expf(e - M) * invS : 0.f;
    }
}

extern "C" void kernel_launch(void* const* d_in, const int* in_sizes, int n_in,
                              void* d_out, int out_size, void* d_ws, size_t ws_size,
                              hipStream_t stream) {
    const float* seq     = (const float*)d_in[0];   // [B,L,D]
    const float* query   = (const float*)d_in[1];   // [B,C]
    const int*   lengths = (const int*)  d_in[2];   // [B]
    const float* W_h     = (const float*)d_in[3];   // [C,D]
    const float* b_h     = (const float*)d_in[4];   // [C]

    float* out    = (float*)d_out;
    float* ctx    = out;                 // [B,D]
    float* scores = out + B_ * D_;       // [B,L]

    float* ws    = (float*)d_ws;
    float* v     = ws;
    float* cb    = ws + 32768;
    float* energ = ws + 32800;
    float* vpart = ws + 98336;
    float* pm    = ws + 622624;
    float* ps    = ws + 624672;
    float* pc    = ws + 626720;
    int*   cnt   = (int*)(ws + 2723872);  // cnt_dc[16], done[32]
    int*   done  = cnt + 16;

    hipMemsetAsync(cnt, 0, 48 * sizeof(int), stream);
    k_prep<<<dim3(16, 16), 256, 0, stream>>>(query, W_h, b_h, vpart, v, cb, cnt);
    k_mega<<<dim3(NCH, B_), 256, 0, stream>>>(seq, v, cb, lengths, energ, pm, ps, pc,
                                              done, ctx, scores);
}

// Round 5
// 68.814 us; speedup vs baseline: 2.3310x; 2.3310x over previous
//
#include <hip/hip_runtime.h>
#include <math.h>

#define B_ 32
#define L_ 2048
#define D_ 1024
#define C_ 1024
#define WROWS 8            // rows per wave in fused kernel
#define BROWS 32           // rows per block (4 waves)
#define NCH (L_ / BROWS)   // 64 chunks per batch row

// ws float offsets:
//   v     : [B_, D_]          0
//   cb    : [B_]              32768
//   energ : [B_, L_]          32800
//   pm    : [B_, NCH]         622624
//   ps    : [B_, NCH]         624672
//   pc    : [B_, NCH, D_]     626720

// ---- K1: v[b,d] = sum_c q[b,c] * W[c,d]; cb[b] = dot(b_h, q[b]) ----
// Grid (16 dc, 8 bg). Block: 4 q-rows in LDS, stream W[:, dc-slice].
__global__ __launch_bounds__(256) void k_v(const float* __restrict__ q,
                                           const float* __restrict__ W,
                                           const float* __restrict__ bh,
                                           float* __restrict__ v,
                                           float* __restrict__ cb) {
    int dc = blockIdx.x;                 // 0..15 (64-wide d slice)
    int bg = blockIdx.y;                 // 0..7  (4 b's)
    int t  = threadIdx.x;
    __shared__ float qs[4][C_];          // 16 KB
    #pragma unroll
    for (int i = 0; i < 4; ++i) {
        int idx = t + i * 256;           // 1024 float4 slots
        int bl = idx >> 8, c4 = idx & 255;
        *reinterpret_cast<float4*>(&qs[bl][c4 * 4]) =
            *reinterpret_cast<const float4*>(q + (size_t)(bg * 4 + bl) * C_ + c4 * 4);
    }
    __syncthreads();

    int dl = t & 63, bl = t >> 6;        // wave bl, lane dl
    int d = dc * 64 + dl;
    float a0 = 0.f, a1 = 0.f;
    for (int c = 0; c < C_; c += 2) {    // 2 accumulators: break fma dep chain
        a0 = fmaf(qs[bl][c],     W[(size_t)c * D_ + d],        a0);
        a1 = fmaf(qs[bl][c + 1], W[(size_t)(c + 1) * D_ + d],  a1);
    }
    v[(size_t)(bg * 4 + bl) * D_ + d] = a0 + a1;

    if (dc == 0) {                       // cb for this block's 4 b's
        float s = 0.f;
        for (int c = dl; c < C_; c += 64) s = fmaf(bh[c], qs[bl][c], s);
        #pragma unroll
        for (int off = 32; off; off >>= 1) s += __shfl_xor(s, off);
        if (dl == 0) cb[bg * 4 + bl] = s;
    }
}

// ---- K2 fused: energies + online-softmax context partials, ONE seq pass ----
__global__ __launch_bounds__(256) void k_fused(const float* __restrict__ seq,
                                               const float* __restrict__ v,
                                               const float* __restrict__ cb,
                                               const int* __restrict__ lenp,
                                               float* __restrict__ energ,
                                               float* __restrict__ pm,
                                               float* __restrict__ ps,
                                               float* __restrict__ pc) {
    int b  = blockIdx.y;
    int ch = blockIdx.x;
    int len = lenp[b];
    int l0 = ch * BROWS;
    if (l0 >= len) return;                       // partial never read downstream
    int wid = threadIdx.x >> 6, lane = threadIdx.x & 63;
    int t = threadIdx.x;
    int lw0 = l0 + wid * WROWS;

    const float* vb = v + (size_t)b * D_;
    float4 v0 = *reinterpret_cast<const float4*>(vb +       lane * 4);
    float4 v1 = *reinterpret_cast<const float4*>(vb + 256 + lane * 4);
    float4 v2 = *reinterpret_cast<const float4*>(vb + 512 + lane * 4);
    float4 v3 = *reinterpret_cast<const float4*>(vb + 768 + lane * 4);
    float cbb = cb[b];

    float m = -INFINITY, s = 0.f;
    float c[16];
    #pragma unroll
    for (int i = 0; i < 16; ++i) c[i] = 0.f;

    __shared__ float e_sm[BROWS];
    __shared__ float lm[4], ls[4];
    __shared__ float lc[4][D_];                  // 16 KB

    if (lw0 < len) {
        #pragma unroll
        for (int r = 0; r < WROWS; ++r) {
            int l = lw0 + r;
            bool valid = l < len;
            const float* row = seq + ((size_t)b * L_ + l) * D_;
            float4 s0 = *reinterpret_cast<const float4*>(row +       lane * 4);
            float4 s1 = *reinterpret_cast<const float4*>(row + 256 + lane * 4);
            float4 s2 = *reinterpret_cast<const float4*>(row + 512 + lane * 4);
            float4 s3 = *reinterpret_cast<const float4*>(row + 768 + lane * 4);
            float acc = 0.f;
            acc = fmaf(s0.x, v0.x, acc); acc = fmaf(s0.y, v0.y, acc);
            acc = fmaf(s0.z, v0.z, acc); acc = fmaf(s0.w, v0.w, acc);
            acc = fmaf(s1.x, v1.x, acc); acc = fmaf(s1.y, v1.y, acc);
            acc = fmaf(s1.z, v1.z, acc); acc = fmaf(s1.w, v1.w, acc);
            acc = fmaf(s2.x, v2.x, acc); acc = fmaf(s2.y, v2.y, acc);
            acc = fmaf(s2.z, v2.z, acc); acc = fmaf(s2.w, v2.w, acc);
            acc = fmaf(s3.x, v3.x, acc); acc = fmaf(s3.y, v3.y, acc);
            acc = fmaf(s3.z, v3.z, acc); acc = fmaf(s3.w, v3.w, acc);
            #pragma unroll
            for (int off = 32; off; off >>= 1) acc += __shfl_xor(acc, off);
            float e = acc + cbb;
            if (lane == 0) e_sm[wid * WROWS + r] = e;
            float mnew  = valid ? fmaxf(m, e) : m;
            float scale = (m == mnew) ? 1.f : __expf(m - mnew);  // handles -inf==-inf
            float p     = valid ? __expf(e - mnew) : 0.f;
            s = s * scale + p;
            c[ 0] = fmaf(p, s0.x, c[ 0] * scale); c[ 1] = fmaf(p, s0.y, c[ 1] * scale);
            c[ 2] = fmaf(p, s0.z, c[ 2] * scale); c[ 3] = fmaf(p, s0.w, c[ 3] * scale);
            c[ 4] = fmaf(p, s1.x, c[ 4] * scale); c[ 5] = fmaf(p, s1.y, c[ 5] * scale);
            c[ 6] = fmaf(p, s1.z, c[ 6] * scale); c[ 7] = fmaf(p, s1.w, c[ 7] * scale);
            c[ 8] = fmaf(p, s2.x, c[ 8] * scale); c[ 9] = fmaf(p, s2.y, c[ 9] * scale);
            c[10] = fmaf(p, s2.z, c[10] * scale); c[11] = fmaf(p, s2.w, c[11] * scale);
            c[12] = fmaf(p, s3.x, c[12] * scale); c[13] = fmaf(p, s3.y, c[13] * scale);
            c[14] = fmaf(p, s3.z, c[14] * scale); c[15] = fmaf(p, s3.w, c[15] * scale);
            m = mnew;
        }
    }

    {
        float4 w0 = {c[ 0], c[ 1], c[ 2], c[ 3]};
        float4 w1 = {c[ 4], c[ 5], c[ 6], c[ 7]};
        float4 w2 = {c[ 8], c[ 9], c[10], c[11]};
        float4 w3 = {c[12], c[13], c[14], c[15]};
        *reinterpret_cast<float4*>(&lc[wid][      lane * 4]) = w0;
        *reinterpret_cast<float4*>(&lc[wid][256 + lane * 4]) = w1;
        *reinterpret_cast<float4*>(&lc[wid][512 + lane * 4]) = w2;
        *reinterpret_cast<float4*>(&lc[wid][768 + lane * 4]) = w3;
        if (lane == 0) { lm[wid] = m; ls[wid] = s; }
    }
    __syncthreads();

    if (t < BROWS) energ[(size_t)b * L_ + l0 + t] = e_sm[t];

    float mb = fmaxf(fmaxf(lm[0], lm[1]), fmaxf(lm[2], lm[3]));
    float w0 = (lm[0] == mb) ? 1.f : __expf(lm[0] - mb);
    float w1 = (lm[1] == mb) ? 1.f : __expf(lm[1] - mb);
    float w2 = (lm[2] == mb) ? 1.f : __expf(lm[2] - mb);
    float w3 = (lm[3] == mb) ? 1.f : __expf(lm[3] - mb);
    float sb = w0 * ls[0] + w1 * ls[1] + w2 * ls[2] + w3 * ls[3];

    float4 a0 = *reinterpret_cast<const float4*>(&lc[0][t * 4]);
    float4 a1 = *reinterpret_cast<const float4*>(&lc[1][t * 4]);
    float4 a2 = *reinterpret_cast<const float4*>(&lc[2][t * 4]);
    float4 a3 = *reinterpret_cast<const float4*>(&lc[3][t * 4]);
    float4 o;
    o.x = w0 * a0.x + w1 * a1.x + w2 * a2.x + w3 * a3.x;
    o.y = w0 * a0.y + w1 * a1.y + w2 * a2.y + w3 * a3.y;
    o.z = w0 * a0.z + w1 * a1.z + w2 * a2.z + w3 * a3.z;
    o.w = w0 * a0.w + w1 * a1.w + w2 * a2.w + w3 * a3.w;

    size_t pidx = (size_t)b * NCH + ch;
    if (t == 0) { pm[pidx] = mb; ps[pidx] = sb; }
    *reinterpret_cast<float4*>(pc + pidx * D_ + t * 4) = o;
}

// ---- K3: per-(b, slice) final merge -> contexts + scores. 256 blocks. ----
__global__ __launch_bounds__(256) void k_final(const float* __restrict__ pm,
                                               const float* __restrict__ ps,
                                               const float* __restrict__ pc,
                                               const float* __restrict__ energ,
                                               const int* __restrict__ lenp,
                                               float* __restrict__ ctx,
                                               float* __restrict__ scores) {
    int b = blockIdx.x, sl = blockIdx.y, t = threadIdx.x;
    int len = lenp[b];
    int nch = (len + BROWS - 1) / BROWS;         // 1..64
    __shared__ float wgt[NCH];
    __shared__ float Msh, Ssh;
    if (t < 64) {
        float mi = (t < nch) ? pm[(size_t)b * NCH + t] : -INFINITY;
        float si = (t < nch) ? ps[(size_t)b * NCH + t] : 0.f;
        float M = mi;
        #pragma unroll
        for (int off = 32; off; off >>= 1) M = fmaxf(M, __shfl_xor(M, off));
        float ew = (t < nch) ? __expf(mi - M) : 0.f;
        float S  = ew * si;
        #pragma unroll
        for (int off = 32; off; off >>= 1) S += __shfl_xor(S, off);
        if (t < nch) wgt[t] = ew / S;
        if (t == 0) { Msh = M; Ssh = S; }
    }
    __syncthreads();
    float M = Msh;
    float invS = 1.f / Ssh;

    if (t < 128) {                               // context slice: 128 d's
        int d = sl * 128 + t;
        float o = 0.f;
        for (int ch = 0; ch < nch; ++ch)
            o = fmaf(wgt[ch], pc[((size_t)b * NCH + ch) * D_ + d], o);
        ctx[(size_t)b * D_ + d] = o;
    }

    int l = sl * 256 + t;                        // scores slice: 256 l's
    float e = energ[(size_t)b * L_ + l];
    scores[(size_t)b * L_ + l] = (l < len) ? __expf(e - M) * invS : 0.f;
}

extern "C" void kernel_launch(void* const* d_in, const int* in_sizes, int n_in,
                              void* d_out, int out_size, void* d_ws, size_t ws_size,
                              hipStream_t stream) {
    const float* seq     = (const float*)d_in[0];   // [B,L,D]
    const float* query   = (const float*)d_in[1];   // [B,C]
    const int*   lengths = (const int*)  d_in[2];   // [B]
    const float* W_h     = (const float*)d_in[3];   // [C,D]
    const float* b_h     = (const float*)d_in[4];   // [C]

    float* out    = (float*)d_out;
    float* ctx    = out;                 // [B,D]
    float* scores = out + B_ * D_;       // [B,L]

    float* ws    = (float*)d_ws;
    float* v     = ws;
    float* cb    = ws + 32768;
    float* energ = ws + 32800;
    float* pm    = ws + 622624;
    float* ps    = ws + 624672;
    float* pc    = ws + 626720;

    k_v    <<<dim3(16, 8), 256, 0, stream>>>(query, W_h, b_h, v, cb);
    k_fused<<<dim3(NCH, B_), 256, 0, stream>>>(seq, v, cb, lengths, energ, pm, ps, pc);
    k_final<<<dim3(B_, 8), 256, 0, stream>>>(pm, ps, pc, energ, lengths, ctx, scores);
}

// Round 6
// 45.505 us; speedup vs baseline: 3.5250x; 1.5122x over previous
//
#include <hip/hip_runtime.h>
#include <math.h>

#define B_ 32
#define L_ 2048
#define D_ 1024
#define C_ 1024
#define CSPLIT 16
#define WROWS 8            // rows per wave in fused kernel
#define NWAVE 8            // waves per fused block
#define BROWS 64           // rows per block (8 waves x 8 rows)
#define NCH (L_ / BROWS)   // 32 chunks per batch row

// ws float offsets:
//   v     : [B_, D_]          0        (32768)
//   cb    : [B_]              32768    (32)
//   energ : [B_, L_]          32800    (65536)
//   vpart : [CSPLIT, B_, D_]  98336    (524288)
//   pm    : [B_, NCH]         622624   (1024)
//   ps    : [B_, NCH]         623648   (1024)
//   pc    : [B_, NCH, D_]     624672   (1048576)

// ---- K1a: vpart[cc][b][d] = sum_{c in cc-chunk} q[b,c] * W[c,d] ----
__global__ __launch_bounds__(256) void k_vpart(const float* __restrict__ q,
                                               const float* __restrict__ W,
                                               float* __restrict__ vpart) {
    int cc = blockIdx.x, dc = blockIdx.y;
    int t  = threadIdx.x;
    __shared__ float qs[B_][65];                 // padded: no bank conflicts
    #pragma unroll
    for (int i = 0; i < 8; ++i) {
        int idx = t + i * 256;                   // 2048 = 32*64
        int b = idx >> 6, cl = idx & 63;
        qs[b][cl] = q[b * C_ + cc * 64 + cl];
    }
    __syncthreads();

    int dl4 = t & 15;
    int bg  = t >> 4;
    float4 a0 = {0,0,0,0}, a1 = {0,0,0,0};
    const float4* W4 = reinterpret_cast<const float4*>(W);
    for (int c = 0; c < 64; ++c) {
        float4 w = W4[(size_t)(cc * 64 + c) * (D_ / 4) + dc * 16 + dl4];
        float q0 = qs[bg * 2 + 0][c];
        float q1 = qs[bg * 2 + 1][c];
        a0.x = fmaf(q0, w.x, a0.x); a0.y = fmaf(q0, w.y, a0.y);
        a0.z = fmaf(q0, w.z, a0.z); a0.w = fmaf(q0, w.w, a0.w);
        a1.x = fmaf(q1, w.x, a1.x); a1.y = fmaf(q1, w.y, a1.y);
        a1.z = fmaf(q1, w.z, a1.z); a1.w = fmaf(q1, w.w, a1.w);
    }
    size_t base = ((size_t)cc * B_ + bg * 2) * D_ + dc * 64 + dl4 * 4;
    *reinterpret_cast<float4*>(vpart + base)      = a0;
    *reinterpret_cast<float4*>(vpart + base + D_) = a1;
}

// ---- K1b: reduce vpart -> v;  cb[b] = dot(b_h, query[b]) ----
__global__ __launch_bounds__(256) void k_vreduce(const float* __restrict__ vpart,
                                                 float* __restrict__ v,
                                                 const float* __restrict__ q,
                                                 const float* __restrict__ bh,
                                                 float* __restrict__ cb) {
    int b = blockIdx.x, dq = blockIdx.y, t = threadIdx.x;
    int d = dq * 256 + t;
    float a = 0.f;
    #pragma unroll
    for (int cc = 0; cc < CSPLIT; ++cc)
        a += vpart[((size_t)cc * B_ + b) * D_ + d];
    v[(size_t)b * D_ + d] = a;

    if (dq == 0) {
        float s = 0.f;
        for (int c = t; c < C_; c += 256) s += bh[c] * q[b * C_ + c];
        __shared__ float red[256];
        red[t] = s; __syncthreads();
        for (int off = 128; off > 0; off >>= 1) {
            if (t < off) red[t] += red[t + off];
            __syncthreads();
        }
        if (t == 0) cb[b] = red[0];
    }
}

// ---- K2 fused: 512 threads, 8 waves x 8 rows; deferred-rescale online softmax ----
__global__ __launch_bounds__(512) void k_fused(const float* __restrict__ seq,
                                               const float* __restrict__ v,
                                               const float* __restrict__ cb,
                                               const int* __restrict__ lenp,
                                               float* __restrict__ energ,
                                               float* __restrict__ pm,
                                               float* __restrict__ ps,
                                               float* __restrict__ pc) {
    int b  = blockIdx.y;
    int ch = blockIdx.x;
    int len = lenp[b];
    int l0 = ch * BROWS;
    if (l0 >= len) return;                       // partial never read downstream
    int t = threadIdx.x, wid = t >> 6, lane = t & 63;
    int lw0 = l0 + wid * WROWS;

    const float* vb = v + (size_t)b * D_;
    float4 v0 = *reinterpret_cast<const float4*>(vb +       lane * 4);
    float4 v1 = *reinterpret_cast<const float4*>(vb + 256 + lane * 4);
    float4 v2 = *reinterpret_cast<const float4*>(vb + 512 + lane * 4);
    float4 v3 = *reinterpret_cast<const float4*>(vb + 768 + lane * 4);
    float cbb = cb[b];

    float m = -INFINITY, s = 0.f;
    float c[16];
    #pragma unroll
    for (int i = 0; i < 16; ++i) c[i] = 0.f;

    __shared__ float e_sm[BROWS];
    __shared__ float lm[NWAVE], ls[NWAVE];
    __shared__ float lc[NWAVE][D_];              // 32 KB

    if (lw0 < len) {
        #pragma unroll
        for (int r = 0; r < WROWS; ++r) {
            int l = lw0 + r;
            if (l >= len) break;                 // wave-uniform
            const float* row = seq + ((size_t)b * L_ + l) * D_;
            float4 s0 = *reinterpret_cast<const float4*>(row +       lane * 4);
            float4 s1 = *reinterpret_cast<const float4*>(row + 256 + lane * 4);
            float4 s2 = *reinterpret_cast<const float4*>(row + 512 + lane * 4);
            float4 s3 = *reinterpret_cast<const float4*>(row + 768 + lane * 4);
            float acc = 0.f;
            acc = fmaf(s0.x, v0.x, acc); acc = fmaf(s0.y, v0.y, acc);
            acc = fmaf(s0.z, v0.z, acc); acc = fmaf(s0.w, v0.w, acc);
            acc = fmaf(s1.x, v1.x, acc); acc = fmaf(s1.y, v1.y, acc);
            acc = fmaf(s1.z, v1.z, acc); acc = fmaf(s1.w, v1.w, acc);
            acc = fmaf(s2.x, v2.x, acc); acc = fmaf(s2.y, v2.y, acc);
            acc = fmaf(s2.z, v2.z, acc); acc = fmaf(s2.w, v2.w, acc);
            acc = fmaf(s3.x, v3.x, acc); acc = fmaf(s3.y, v3.y, acc);
            acc = fmaf(s3.z, v3.z, acc); acc = fmaf(s3.w, v3.w, acc);
            #pragma unroll
            for (int off = 32; off; off >>= 1) acc += __shfl_xor(acc, off);
            float e = acc + cbb;                 // wave-uniform after butterfly
            if (lane == 0) e_sm[wid * WROWS + r] = e;
            if (e > m) {                         // wave-uniform branch (rare: ~H(8))
                float sc = __expf(m - e);        // first row: exp(-inf)=0
                s = fmaf(s, sc, 1.f);
                c[ 0] = fmaf(c[ 0], sc, s0.x); c[ 1] = fmaf(c[ 1], sc, s0.y);
                c[ 2] = fmaf(c[ 2], sc, s0.z); c[ 3] = fmaf(c[ 3], sc, s0.w);
                c[ 4] = fmaf(c[ 4], sc, s1.x); c[ 5] = fmaf(c[ 5], sc, s1.y);
                c[ 6] = fmaf(c[ 6], sc, s1.z); c[ 7] = fmaf(c[ 7], sc, s1.w);
                c[ 8] = fmaf(c[ 8], sc, s2.x); c[ 9] = fmaf(c[ 9], sc, s2.y);
                c[10] = fmaf(c[10], sc, s2.z); c[11] = fmaf(c[11], sc, s2.w);
                c[12] = fmaf(c[12], sc, s3.x); c[13] = fmaf(c[13], sc, s3.y);
                c[14] = fmaf(c[14], sc, s3.z); c[15] = fmaf(c[15], sc, s3.w);
                m = e;
            } else {                             // common path: no rescale
                float p = __expf(e - m);
                s += p;
                c[ 0] = fmaf(p, s0.x, c[ 0]); c[ 1] = fmaf(p, s0.y, c[ 1]);
                c[ 2] = fmaf(p, s0.z, c[ 2]); c[ 3] = fmaf(p, s0.w, c[ 3]);
                c[ 4] = fmaf(p, s1.x, c[ 4]); c[ 5] = fmaf(p, s1.y, c[ 5]);
                c[ 6] = fmaf(p, s1.z, c[ 6]); c[ 7] = fmaf(p, s1.w, c[ 7]);
                c[ 8] = fmaf(p, s2.x, c[ 8]); c[ 9] = fmaf(p, s2.y, c[ 9]);
                c[10] = fmaf(p, s2.z, c[10]); c[11] = fmaf(p, s2.w, c[11]);
                c[12] = fmaf(p, s3.x, c[12]); c[13] = fmaf(p, s3.y, c[13]);
                c[14] = fmaf(p, s3.z, c[14]); c[15] = fmaf(p, s3.w, c[15]);
            }
        }
    }

    {
        float4 w0 = {c[ 0], c[ 1], c[ 2], c[ 3]};
        float4 w1 = {c[ 4], c[ 5], c[ 6], c[ 7]};
        float4 w2 = {c[ 8], c[ 9], c[10], c[11]};
        float4 w3 = {c[12], c[13], c[14], c[15]};
        *reinterpret_cast<float4*>(&lc[wid][      lane * 4]) = w0;
        *reinterpret_cast<float4*>(&lc[wid][256 + lane * 4]) = w1;
        *reinterpret_cast<float4*>(&lc[wid][512 + lane * 4]) = w2;
        *reinterpret_cast<float4*>(&lc[wid][768 + lane * 4]) = w3;
        if (lane == 0) { lm[wid] = m; ls[wid] = s; }
    }
    __syncthreads();

    if (t < BROWS) energ[(size_t)b * L_ + l0 + t] = e_sm[t];

    // 8-way combine (weights wave-uniform; empty waves have lm=-inf -> w=0)
    float mb = lm[0];
    #pragma unroll
    for (int i = 1; i < NWAVE; ++i) mb = fmaxf(mb, lm[i]);
    float wgt[NWAVE], sb = 0.f;
    #pragma unroll
    for (int i = 0; i < NWAVE; ++i) {
        wgt[i] = (lm[i] == mb) ? 1.f : __expf(lm[i] - mb);
        sb = fmaf(wgt[i], ls[i], sb);
    }

    // each thread combines 2 d's (512 threads x 2 = 1024)
    float ox = 0.f, oy = 0.f;
    #pragma unroll
    for (int i = 0; i < NWAVE; ++i) {
        ox = fmaf(wgt[i], lc[i][t * 2],     ox);
        oy = fmaf(wgt[i], lc[i][t * 2 + 1], oy);
    }
    size_t pidx = (size_t)b * NCH + ch;
    if (t == 0) { pm[pidx] = mb; ps[pidx] = sb; }
    float2 o2 = {ox, oy};
    *reinterpret_cast<float2*>(pc + pidx * D_ + t * 2) = o2;
}

// ---- K3: per-(b, slice) final merge -> contexts + scores. 256 blocks. ----
__global__ __launch_bounds__(256) void k_final(const float* __restrict__ pm,
                                               const float* __restrict__ ps,
                                               const float* __restrict__ pc,
                                               const float* __restrict__ energ,
                                               const int* __restrict__ lenp,
                                               float* __restrict__ ctx,
                                               float* __restrict__ scores) {
    int b = blockIdx.x, sl = blockIdx.y, t = threadIdx.x;
    int len = lenp[b];
    int nch = (len + BROWS - 1) / BROWS;         // 1..32
    __shared__ float wgt[NCH];
    __shared__ float Msh, Ssh;
    if (t < 64) {
        float mi = (t < nch) ? pm[(size_t)b * NCH + t] : -INFINITY;
        float si = (t < nch) ? ps[(size_t)b * NCH + t] : 0.f;
        float M = mi;
        #pragma unroll
        for (int off = 32; off; off >>= 1) M = fmaxf(M, __shfl_xor(M, off));
        float ew = (t < nch) ? __expf(mi - M) : 0.f;
        float S  = ew * si;
        #pragma unroll
        for (int off = 32; off; off >>= 1) S += __shfl_xor(S, off);
        if (t < nch) wgt[t] = ew / S;
        if (t == 0) { Msh = M; Ssh = S; }
    }
    __syncthreads();
    float M = Msh;
    float invS = 1.f / Ssh;

    if (t < 128) {                               // context slice: 128 d's
        int d = sl * 128 + t;
        float o = 0.f;
        for (int ch = 0; ch < nch; ++ch)
            o = fmaf(wgt[ch], pc[((size_t)b * NCH + ch) * D_ + d], o);
        ctx[(size_t)b * D_ + d] = o;
    }

    int l = sl * 256 + t;                        // scores slice: 256 l's
    float e = energ[(size_t)b * L_ + l];
    scores[(size_t)b * L_ + l] = (l < len) ? __expf(e - M) * invS : 0.f;
}

extern "C" void kernel_launch(void* const* d_in, const int* in_sizes, int n_in,
                              void* d_out, int out_size, void* d_ws, size_t ws_size,
                              hipStream_t stream) {
    const float* seq     = (const float*)d_in[0];   // [B,L,D]
    const float* query   = (const float*)d_in[1];   // [B,C]
    const int*   lengths = (const int*)  d_in[2];   // [B]
    const float* W_h     = (const float*)d_in[3];   // [C,D]
    const float* b_h     = (const float*)d_in[4];   // [C]

    float* out    = (float*)d_out;
    float* ctx    = out;                 // [B,D]
    float* scores = out + B_ * D_;       // [B,L]

    float* ws    = (float*)d_ws;
    float* v     = ws;
    float* cb    = ws + 32768;
    float* energ = ws + 32800;
    float* vpart = ws + 98336;
    float* pm    = ws + 622624;
    float* ps    = ws + 623648;
    float* pc    = ws + 624672;

    k_vpart  <<<dim3(16, 16), 256, 0, stream>>>(query, W_h, vpart);
    k_vreduce<<<dim3(B_, 4), 256, 0, stream>>>(vpart, v, query, b_h, cb);
    k_fused  <<<dim3(NCH, B_), 512, 0, stream>>>(seq, v, cb, lengths, energ, pm, ps, pc);
    k_final  <<<dim3(B_, 8), 256, 0, stream>>>(pm, ps, pc, energ, lengths, ctx, scores);
}